// Round 11
// baseline (165.959 us; speedup 1.0000x reference)
//
#include <hip/hip_runtime.h>
#include <hip/hip_fp16.h>
#include <math.h>

// Problem constants (from reference)
#define NN 20000          // nodes
#define TT 4              // time steps
#define EE 320000         // edges
#define NT (NN*TT)        // 80000 rows
#define H1 8              // heads layer 1
#define C1 128            // heads*f_out layer 1
#define IN_F 32
#define OUT_F 16
#define CAP 96            // bucket capacity; max degree Poisson(16) << 96
#define SCAT_BLOCKS 313   // ceil((EE/4)/256)
#define XCAST_BLOCKS 1250 // NT/64

typedef _Float16 h8 __attribute__((ext_vector_type(8)));
typedef float f32x4 __attribute__((ext_vector_type(4)));

__device__ __forceinline__ float lrelu_exp(float e) {
  e = (e >= 0.f) ? e : 0.2f * e;
  return __expf(e);
}

// ---------------------------------------------------------------------------
// K1 "front": unchanged (R18-locked merged layout).
// ---------------------------------------------------------------------------
__global__ __launch_bounds__(256) void k_front(
    const float* __restrict__ x, const float* __restrict__ W1,
    const float* __restrict__ al1, const float* __restrict__ ar1,
    const float* __restrict__ W2, const float* __restrict__ al2,
    const float* __restrict__ ar2,
    const int4* __restrict__ src4, const int4* __restrict__ dst4,
    int* __restrict__ cnt, int* __restrict__ csr96,
    __half* __restrict__ xh, float* __restrict__ el1, float* __restrict__ er1,
    __half* __restrict__ W1hp, __half* __restrict__ W2pp) {
  __shared__ h8 ELERs[64];               // 1 KB, xcast branch only
  int b = blockIdx.x;
  int tid = threadIdx.x;
  if (b < SCAT_BLOCKS) {
    int e4 = b * 256 + tid;
    if (e4 < EE / 4) {
      int4 s = src4[e4];
      int4 d = dst4[e4];
      int p0 = atomicAdd(&cnt[d.x], 1); csr96[d.x * CAP + p0] = s.x;
      int p1 = atomicAdd(&cnt[d.y], 1); csr96[d.y * CAP + p1] = s.y;
      int p2 = atomicAdd(&cnt[d.z], 1); csr96[d.z * CAP + p2] = s.z;
      int p3 = atomicAdd(&cnt[d.w], 1); csr96[d.w * CAP + p3] = s.w;
    }
    return;
  }
  if (b == SCAT_BLOCKS) {
    for (int idx = tid; idx < 8 * 512; idx += 256) {
      int tile = idx >> 9;
      int rem = idx & 511;
      int lane = rem >> 3, j = rem & 7;
      int k = (lane >> 4) * 8 + j;
      int n = lane & 15;
      W1hp[idx] = __float2half(W1[k * C1 + tile * 16 + n]);
    }
    for (int idx = tid; idx < 8 * 512; idx += 256) {
      int tile = idx >> 9;
      int rem = idx & 511;
      int lane = rem >> 3, j = rem & 7;
      int ks = tile & 3;
      int k = ks * 32 + (lane >> 4) * 8 + j;
      int n = lane & 15;
      float v = 0.f;
      if (tile < 4) {
        v = W2[k * OUT_F + n];
      } else if (n == 0) {
        float s = 0.f;
        for (int f = 0; f < 16; ++f) s += W2[k * OUT_F + f] * al2[f];
        v = s;
      } else if (n == 1) {
        float s = 0.f;
        for (int f = 0; f < 16; ++f) s += W2[k * OUT_F + f] * ar2[f];
        v = s;
      }
      W2pp[idx] = __float2half(v);
    }
    return;
  }
  // ---- xcast + el/er branch ----
  {
    __half* E = (__half*)ELERs;
    for (int idx = tid; idx < 512; idx += 256) {
      int lane = idx >> 3, j = idx & 7;
      int k = (lane >> 4) * 8 + j;
      int n = lane & 15;
      int hh_ = n & 7;
      const float* a = (n < 8) ? al1 : ar1;
      float s = 0.f;
      for (int f = 0; f < 16; ++f) s += W1[k * C1 + hh_ * 16 + f] * a[hh_ * 16 + f];
      E[idx] = __float2half(s);
    }
  }
  __syncthreads();
  int wave = tid >> 6, lane = tid & 63;
  int m = lane & 15, quad = lane >> 4;
  int rowbase = (b - SCAT_BLOCKS - 1) * 64 + wave * 16;
  int row = rowbase + m;
  const float4* xp = (const float4*)(x + row * IN_F + quad * 8);
  float4 a0 = xp[0], a1 = xp[1];
  h8 af;
  af[0] = (_Float16)a0.x; af[1] = (_Float16)a0.y;
  af[2] = (_Float16)a0.z; af[3] = (_Float16)a0.w;
  af[4] = (_Float16)a1.x; af[5] = (_Float16)a1.y;
  af[6] = (_Float16)a1.z; af[7] = (_Float16)a1.w;
  *(h8*)(xh + (size_t)row * IN_F + quad * 8) = af;   // fp16 x copy
  {
    h8 bf = ELERs[lane];
    f32x4 c = {0.f, 0.f, 0.f, 0.f};
    c = __builtin_amdgcn_mfma_f32_16x16x32_f16(af, bf, c, 0, 0, 0);
#pragma unroll
    for (int r = 0; r < 4; ++r) {
      int orow = rowbase + quad * 4 + r;
      if (m < 8) el1[orow * H1 + m] = c[r];
      else       er1[orow * H1 + (m - 8)] = c[r];
    }
  }
}

// ---------------------------------------------------------------------------
// K2: layer-1 x-form aggregate — baseline load pattern (low-BW, long:
// the fill-hiding window; R21 staged variant banned, see R6-R9) with R25
// change: 2-DEEP SOFTWARE PIPELINE. Ping-pong A/B register sets: issue
// group g+1's gathers, then consume group g — overlaps each gather round's
// wait with the previous group's ~150cyc consume. Staging = 2x36 VGPR
// (vs R3's flat 8-wide which tipped the 128 cliff). Consumption order
// strictly sequential -> bitwise-identical accumulation. pk_fma CONSUME
// arithmetic LOCKED (R11-R16); fused mid-GEMM epilogue unchanged.
// ---------------------------------------------------------------------------
__global__ __launch_bounds__(256) void k_agg1m(
    const __half* __restrict__ xh,       // [nt][32]
    const float* __restrict__ el1,       // [n][32] = [n][t][8]
    const float* __restrict__ er1,
    const int* __restrict__ cnt, const int* __restrict__ csr96,
    const __half* __restrict__ W1hp, const float* __restrict__ b1,
    const __half* __restrict__ W2pp,
    __half* __restrict__ feat2h, float* __restrict__ el2,
    float* __restrict__ er2) {
  __shared__ __half axs[16][264];        // 8.4 KB aggx tile, stride-264 pad
  __shared__ __half hs[16][136];         // 4.3 KB h tile, stride-136 pad
  int tid = threadIdx.x;
  int wv = tid >> 6, lane = tid & 63;
  int n = blockIdx.x * 4 + wv;
  int slot = lane >> 1;                  // (t,h): t=slot>>3, h=slot&7
  int t = lane >> 4;                     // == slot>>3
  int hf = lane & 1;
  float er_i = er1[(size_t)n * 32 + slot];
  int deg = cnt[n];
  const int* eb = csr96 + (size_t)n * CAP;
  h8 accA = {0, 0, 0, 0, 0, 0, 0, 0};
  h8 accB = {0, 0, 0, 0, 0, 0, 0, 0};
  float l = 0.f;
  for (int chunk = 0; chunk < deg; chunk += 64) {
    int m = min(64, deg - chunk);
    int sv = (lane < m) ? eb[chunk + lane] : 0;
    int iters = (m + 3) >> 2;
    // ping-pong staging registers
    float ewA0, ewA1, ewA2, ewA3, ewB0, ewB1, ewB2, ewB3;
    h8 xaA0, xaA1, xaA2, xaA3, xbA0, xbA1, xbA2, xbA3;
    h8 xaB0, xaB1, xaB2, xaB3, xbB0, xbB1, xbB2, xbB3;
#define LOADG(S, G)                                                       \
    {                                                                     \
      int j_ = (G) * 4;                                                   \
      int s0 = __builtin_amdgcn_readlane(sv, j_ + 0);                     \
      int s1 = __builtin_amdgcn_readlane(sv, j_ + 1);                     \
      int s2 = __builtin_amdgcn_readlane(sv, j_ + 2);                     \
      int s3 = __builtin_amdgcn_readlane(sv, j_ + 3);                     \
      ew##S##0 = el1[(size_t)s0 * 32 + slot];                             \
      ew##S##1 = el1[(size_t)s1 * 32 + slot];                             \
      ew##S##2 = el1[(size_t)s2 * 32 + slot];                             \
      ew##S##3 = el1[(size_t)s3 * 32 + slot];                             \
      const __half* x0 = xh + (size_t)(s0 * 4 + t) * 32 + hf * 16;        \
      const __half* x1 = xh + (size_t)(s1 * 4 + t) * 32 + hf * 16;        \
      const __half* x2 = xh + (size_t)(s2 * 4 + t) * 32 + hf * 16;        \
      const __half* x3 = xh + (size_t)(s3 * 4 + t) * 32 + hf * 16;        \
      xa##S##0 = *(const h8*)x0; xb##S##0 = *(const h8*)(x0 + 8);         \
      xa##S##1 = *(const h8*)x1; xb##S##1 = *(const h8*)(x1 + 8);         \
      xa##S##2 = *(const h8*)x2; xb##S##2 = *(const h8*)(x2 + 8);         \
      xa##S##3 = *(const h8*)x3; xb##S##3 = *(const h8*)(x3 + 8);         \
    }
#define CONS1(JK, EW, XA, XB)                                             \
    {                                                                     \
      float w_ = lrelu_exp(EW + er_i);                                    \
      w_ = ((JK) < m) ? w_ : 0.f;                                         \
      l += w_;                                                            \
      _Float16 wh_ = (_Float16)w_;                                        \
      h8 w8_ = {wh_, wh_, wh_, wh_, wh_, wh_, wh_, wh_};                  \
      accA += w8_ * XA;                                                   \
      accB += w8_ * XB;                                                   \
    }
#define CONSG(S, G)                                                       \
    {                                                                     \
      int j_ = (G) * 4;                                                   \
      CONS1(j_ + 0, ew##S##0, xa##S##0, xb##S##0)                         \
      CONS1(j_ + 1, ew##S##1, xa##S##1, xb##S##1)                         \
      CONS1(j_ + 2, ew##S##2, xa##S##2, xb##S##2)                         \
      CONS1(j_ + 3, ew##S##3, xa##S##3, xb##S##3)                         \
    }
    LOADG(A, 0)
    int g = 0;
    for (; g + 1 < iters; g += 2) {
      LOADG(B, g + 1)
      CONSG(A, g)
      if (g + 2 < iters) LOADG(A, g + 2)
      CONSG(B, g + 1)
    }
    if (g < iters) CONSG(A, g)
#undef LOADG
#undef CONS1
#undef CONSG
  }
  float inv = (l > 0.f) ? (1.f / l) : 0.f;
  {
    h8 r0, r1;
#pragma unroll
    for (int q = 0; q < 8; ++q) {
      r0[q] = (_Float16)((float)accA[q] * inv);
      r1[q] = (_Float16)((float)accB[q] * inv);
    }
    int hh_ = slot & 7;
    __half* op = &axs[wv * 4 + t][hh_ * 32 + hf * 16];
    *(h8*)op = r0;
    *(h8*)(op + 8) = r1;
  }
  __syncthreads();

  // ---- fused mid epilogue (barrier-fenced, cold code) ----
  int m = lane & 15, quad = lane >> 4;
  const h8* bp1 = (const h8*)W1hp;
#pragma unroll
  for (int hi = 0; hi < 2; ++hi) {
    int head = wv * 2 + hi;
    h8 af = *(const h8*)&axs[m][head * 32 + quad * 8];
    f32x4 c = {0.f, 0.f, 0.f, 0.f};
    c = __builtin_amdgcn_mfma_f32_16x16x32_f16(af, bp1[head * 64 + lane], c, 0, 0, 0);
    float bv = b1[head * 16 + m];
#pragma unroll
    for (int r = 0; r < 4; ++r)
      hs[quad * 4 + r][head * 16 + m] = __float2half(c[r] + bv);
  }
  __syncthreads();
  if (wv != 0) return;
  const h8* bp2 = (const h8*)W2pp;
  f32x4 cF = {0.f, 0.f, 0.f, 0.f};
  f32x4 cE = {0.f, 0.f, 0.f, 0.f};
#pragma unroll
  for (int ks = 0; ks < 4; ++ks) {
    h8 af = *(const h8*)&hs[m][ks * 32 + quad * 8];
    cF = __builtin_amdgcn_mfma_f32_16x16x32_f16(af, bp2[ks * 64 + lane], cF, 0, 0, 0);
    cE = __builtin_amdgcn_mfma_f32_16x16x32_f16(af, bp2[(4 + ks) * 64 + lane], cE, 0, 0, 0);
  }
#pragma unroll
  for (int r = 0; r < 4; ++r) {
    int orow = blockIdx.x * 16 + quad * 4 + r;
    feat2h[(size_t)orow * OUT_F + m] = __float2half(cF[r]);
    if (m == 0) el2[orow] = cE[r];
    if (m == 1) er2[orow] = cE[r];
  }
}

// ---------------------------------------------------------------------------
// K3: layer-2 aggregate — baseline coalesced load pattern (staged form was
// exactly neutral, R10) with the same R25 2-deep pipeline over 8-edge
// groups (~16 extra VGPRs). Consumption order sequential -> results
// bitwise-identical to baseline. One wave per node; lane=(t,f).
// ---------------------------------------------------------------------------
__global__ __launch_bounds__(256) void k_agg2x(
    const __half* __restrict__ feat2h,   // [nt][16]
    const float* __restrict__ el2, const float* __restrict__ er2,  // [nt]
    const int* __restrict__ cnt, const int* __restrict__ csr96,
    const float* __restrict__ b2, float* __restrict__ out) {
  int tid = threadIdx.x;
  int wv = tid >> 6, lane = tid & 63;
  int n = blockIdx.x * 4 + wv;
  int t = lane >> 4, f = lane & 15;
  float ern = er2[n * 4 + t];
  int deg = cnt[n];
  const int* eb = csr96 + (size_t)n * CAP;
  float acc = 0.f, l = 0.f;
  for (int chunk = 0; chunk < deg; chunk += 64) {
    int m = min(64, deg - chunk);
    int sv = (lane < m) ? eb[chunk + lane] : 0;
    int iters = (m + 7) >> 3;
    float eA0, eA1, eA2, eA3, eA4, eA5, eA6, eA7;
    float eB0, eB1, eB2, eB3, eB4, eB5, eB6, eB7;
    __half hA0, hA1, hA2, hA3, hA4, hA5, hA6, hA7;
    __half hB0, hB1, hB2, hB3, hB4, hB5, hB6, hB7;
#define LOADG2(S, G)                                                      \
    {                                                                     \
      int j_ = (G) * 8;                                                   \
      int s0 = __builtin_amdgcn_readlane(sv, j_ + 0);                     \
      int s1 = __builtin_amdgcn_readlane(sv, j_ + 1);                     \
      int s2 = __builtin_amdgcn_readlane(sv, j_ + 2);                     \
      int s3 = __builtin_amdgcn_readlane(sv, j_ + 3);                     \
      int s4 = __builtin_amdgcn_readlane(sv, j_ + 4);                     \
      int s5 = __builtin_amdgcn_readlane(sv, j_ + 5);                     \
      int s6 = __builtin_amdgcn_readlane(sv, j_ + 6);                     \
      int s7 = __builtin_amdgcn_readlane(sv, j_ + 7);                     \
      e##S##0 = el2[s0 * 4 + t];                                          \
      e##S##1 = el2[s1 * 4 + t];                                          \
      e##S##2 = el2[s2 * 4 + t];                                          \
      e##S##3 = el2[s3 * 4 + t];                                          \
      e##S##4 = el2[s4 * 4 + t];                                          \
      e##S##5 = el2[s5 * 4 + t];                                          \
      e##S##6 = el2[s6 * 4 + t];                                          \
      e##S##7 = el2[s7 * 4 + t];                                          \
      h##S##0 = feat2h[(size_t)(s0 * 4 + t) * OUT_F + f];                 \
      h##S##1 = feat2h[(size_t)(s1 * 4 + t) * OUT_F + f];                 \
      h##S##2 = feat2h[(size_t)(s2 * 4 + t) * OUT_F + f];                 \
      h##S##3 = feat2h[(size_t)(s3 * 4 + t) * OUT_F + f];                 \
      h##S##4 = feat2h[(size_t)(s4 * 4 + t) * OUT_F + f];                 \
      h##S##5 = feat2h[(size_t)(s5 * 4 + t) * OUT_F + f];                 \
      h##S##6 = feat2h[(size_t)(s6 * 4 + t) * OUT_F + f];                 \
      h##S##7 = feat2h[(size_t)(s7 * 4 + t) * OUT_F + f];                 \
    }
#define CONS2(JK, EW, FV)                                                 \
    {                                                                     \
      float w_ = lrelu_exp(EW + ern);                                     \
      w_ = ((JK) < m) ? w_ : 0.f;                                         \
      l += w_;                                                            \
      acc = fmaf(w_, __half2float(FV), acc);                              \
    }
#define CONSG2(S, G)                                                      \
    {                                                                     \
      int j_ = (G) * 8;                                                   \
      CONS2(j_ + 0, e##S##0, h##S##0)                                     \
      CONS2(j_ + 1, e##S##1, h##S##1)                                     \
      CONS2(j_ + 2, e##S##2, h##S##2)                                     \
      CONS2(j_ + 3, e##S##3, h##S##3)                                     \
      CONS2(j_ + 4, e##S##4, h##S##4)                                     \
      CONS2(j_ + 5, e##S##5, h##S##5)                                     \
      CONS2(j_ + 6, e##S##6, h##S##6)                                     \
      CONS2(j_ + 7, e##S##7, h##S##7)                                     \
    }
    LOADG2(A, 0)
    int g = 0;
    for (; g + 1 < iters; g += 2) {
      LOADG2(B, g + 1)
      CONSG2(A, g)
      if (g + 2 < iters) LOADG2(A, g + 2)
      CONSG2(B, g + 1)
    }
    if (g < iters) CONSG2(A, g)
#undef LOADG2
#undef CONS2
#undef CONSG2
  }
  float inv = (l > 0.f) ? (1.f / l) : 0.f;
  out[(size_t)(n * 4 + t) * OUT_F + f] = acc * inv + b2[f];
}

// ---------------------------------------------------------------------------
extern "C" void kernel_launch(void* const* d_in, const int* in_sizes, int n_in,
                              void* d_out, int out_size, void* d_ws, size_t ws_size,
                              hipStream_t stream) {
  const float* x   = (const float*)d_in[0];
  const int*   src = (const int*)d_in[1];
  const int*   dst = (const int*)d_in[2];
  const float* W1  = (const float*)d_in[3];
  const float* al1 = (const float*)d_in[4];
  const float* ar1 = (const float*)d_in[5];
  const float* b1  = (const float*)d_in[6];
  const float* W2  = (const float*)d_in[7];
  const float* al2 = (const float*)d_in[8];
  const float* ar2 = (const float*)d_in[9];
  const float* b2  = (const float*)d_in[10];
  float* out = (float*)d_out;

  // Workspace layout (bytes, 256-aligned chunks), ~22 MB total
  char* w = (char*)d_ws;
  __half* xh     = (__half*)w; w += (size_t)NT * IN_F * 2;      // 5.12 MB
  __half* feat2h = (__half*)w; w += (size_t)NT * OUT_F * 2;     // 2.56 MB
  float*  el1    = (float*)w;  w += (size_t)NT * H1 * 4;        // 2.56 MB
  float*  er1    = (float*)w;  w += (size_t)NT * H1 * 4;
  float*  el2    = (float*)w;  w += (size_t)NT * 4;             // 0.32 MB
  float*  er2    = (float*)w;  w += (size_t)NT * 4;             // contiguous after el2
  __half* W1hp   = (__half*)w; w += (size_t)8 * 512 * 2;
  __half* W2pp   = (__half*)w; w += (size_t)8 * 512 * 2;
  int* cnt     = (int*)w;      w += (size_t)NN * 4;             // 80 KB
  int* csr96   = (int*)w;      w += (size_t)NN * CAP * 4;       // 7.68 MB

  hipMemsetAsync(cnt, 0, NN * sizeof(int), stream);

  k_front<<<SCAT_BLOCKS + 1 + XCAST_BLOCKS, 256, 0, stream>>>(
      x, W1, al1, ar1, W2, al2, ar2, (const int4*)src, (const int4*)dst,
      cnt, csr96, xh, el1, er1, W1hp, W2pp);
  k_agg1m<<<NN / 4, 256, 0, stream>>>(xh, el1, er1, cnt, csr96,
                                      W1hp, b1, W2pp, feat2h, el2, er2);
  k_agg2x<<<NN / 4, 256, 0, stream>>>(feat2h, el2, er2, cnt, csr96, b2, out);
}